// Round 1
// baseline (163.597 us; speedup 1.0000x reference)
//
#include <hip/hip_runtime.h>
#include <math.h>

// Problem constants (B=8, S=1024, D=256, H=16, HD=16)
#define Gz 8192          // B*S rows
#define Dz 256
#define Sz 1024
#define Hz 16

// ---------------------------------------------------------------------------
// K1: out = rope(x @ W^T + b)  for W in {Wq, Wv} (blockIdx.z selects)
// 64x64 block tile, 256 threads, 4x4 register tile per thread, fp32.
// ---------------------------------------------------------------------------
__global__ __launch_bounds__(256) void gemm_rope_kernel(
    const float* __restrict__ x,
    const float* __restrict__ Wq, const float* __restrict__ bq,
    const float* __restrict__ Wv, const float* __restrict__ bv,
    float* __restrict__ xq, float* __restrict__ xv)
{
    __shared__ float As[64][36];   // pad 36: float4-aligned, conflict-light
    __shared__ float Bs[64][36];
    const int t  = threadIdx.x;
    const int tr = t >> 4;         // 0..15, owns rows {tr+16i}
    const int tc = t & 15;         // 0..15, owns cols {tc+16j}
    const int g0 = blockIdx.x * 64;
    const int n0 = blockIdx.y * 64;
    const int sel = blockIdx.z;
    const float* W    = sel ? Wv : Wq;
    const float* bias = sel ? bv : bq;
    float* out        = sel ? xv : xq;

    float acc[4][4];
    #pragma unroll
    for (int i = 0; i < 4; ++i)
        #pragma unroll
        for (int j = 0; j < 4; ++j) acc[i][j] = 0.f;

    for (int k0 = 0; k0 < Dz; k0 += 32) {
        __syncthreads();
        #pragma unroll
        for (int l = 0; l < 8; ++l) {          // 2048 elems each, 8/thread
            int idx = t + l * 256;
            int r = idx >> 5, kk = idx & 31;
            As[r][kk] = x[(size_t)(g0 + r) * Dz + k0 + kk];
            Bs[r][kk] = W[(size_t)(n0 + r) * Dz + k0 + kk];
        }
        __syncthreads();
        #pragma unroll
        for (int kk = 0; kk < 32; kk += 4) {
            float4 a4[4], b4[4];
            #pragma unroll
            for (int i = 0; i < 4; ++i) a4[i] = *(const float4*)&As[tr + 16*i][kk];
            #pragma unroll
            for (int j = 0; j < 4; ++j) b4[j] = *(const float4*)&Bs[tc + 16*j][kk];
            #pragma unroll
            for (int i = 0; i < 4; ++i)
                #pragma unroll
                for (int j = 0; j < 4; ++j) {
                    acc[i][j] = fmaf(a4[i].x, b4[j].x, acc[i][j]);
                    acc[i][j] = fmaf(a4[i].y, b4[j].y, acc[i][j]);
                    acc[i][j] = fmaf(a4[i].z, b4[j].z, acc[i][j]);
                    acc[i][j] = fmaf(a4[i].w, b4[j].w, acc[i][j]);
                }
        }
    }

    // Epilogue: bias + RoPE (rotor = sin + i*cos, 1-indexed pos) + store.
    // Pair partner col = c^1 lives on thread t^1 (same i,j iteration).
    #pragma unroll
    for (int j = 0; j < 4; ++j) {
        const int c = n0 + tc + 16*j;
        const float bcol  = bias[c];
        const float theta = ((c >> 1) < 64) ? 1.0f : 1e-4f;
        const float sign  = (c & 1) ? 1.0f : -1.0f;
        #pragma unroll
        for (int i = 0; i < 4; ++i) {
            const int g = g0 + tr + 16*i;
            float v = acc[i][j] + bcol;
            float other = __shfl_xor(v, 1, 64);
            float ang = (float)((g & (Sz - 1)) + 1) * theta;
            float sn, cs;
            sincosf(ang, &sn, &cs);
            out[(size_t)g * Dz + c] = v * sn + sign * other * cs;
        }
    }
}

// ---------------------------------------------------------------------------
// K2: per (b,h): M[e][f] = 0.25 * sum_s xq[b,s,h*16+e] * xv[b,s,h*16+f]
// 128 blocks (one per b,h), 256 threads = one (e,f) entry each.
// ---------------------------------------------------------------------------
__global__ __launch_bounds__(256) void head_outer_kernel(
    const float* __restrict__ xq, const float* __restrict__ xv,
    float* __restrict__ M)
{
    __shared__ float qsT[16][68];   // transposed: [d][s], pad 68 (16B aligned)
    __shared__ float vsT[16][68];
    const int t  = threadIdx.x;
    const int bh = blockIdx.x;      // b*16 + h
    const int b  = bh >> 4, h = bh & 15;
    const int d1 = t >> 4, d2 = t & 15;
    const size_t base = (size_t)b * Sz * Dz + h * 16;

    float acc = 0.f;
    for (int s0 = 0; s0 < Sz; s0 += 64) {
        __syncthreads();
        #pragma unroll
        for (int l = 0; l < 4; ++l) {          // 1024 elems each, 4/thread
            int idx = t + l * 256;
            int ss = idx >> 4, dd = idx & 15;
            size_t off = base + (size_t)(s0 + ss) * Dz + dd;
            qsT[dd][ss] = xq[off];
            vsT[dd][ss] = xv[off];
        }
        __syncthreads();
        #pragma unroll
        for (int ss = 0; ss < 64; ss += 4) {
            float4 q4 = *(const float4*)&qsT[d1][ss];
            float4 v4 = *(const float4*)&vsT[d2][ss];
            acc = fmaf(q4.x, v4.x, acc);
            acc = fmaf(q4.y, v4.y, acc);
            acc = fmaf(q4.z, v4.z, acc);
            acc = fmaf(q4.w, v4.w, acc);
        }
    }
    M[(size_t)bh * 256 + t] = acc * 0.25f;
}

// ---------------------------------------------------------------------------
// K3a: att[g, h*16+hd] = sum_e xq[g, h*16+e] * M[b,h][e][hd]
// One block per row g, thread per output col.
// ---------------------------------------------------------------------------
__global__ __launch_bounds__(256) void att_kernel(
    const float* __restrict__ xq, const float* __restrict__ M,
    float* __restrict__ att)
{
    const int c = threadIdx.x;
    const int g = blockIdx.x;
    const int h = c >> 4, hd = c & 15;
    const int b = g >> 10;

    const float4* xq4 = (const float4*)(xq + (size_t)g * Dz + h * 16);
    const float*  Mb  = M + ((size_t)(b * Hz + h)) * 256 + hd;

    float a = 0.f;
    #pragma unroll
    for (int q = 0; q < 4; ++q) {
        float4 xv4 = xq4[q];
        a = fmaf(xv4.x, Mb[(4*q + 0) * 16], a);
        a = fmaf(xv4.y, Mb[(4*q + 1) * 16], a);
        a = fmaf(xv4.z, Mb[(4*q + 2) * 16], a);
        a = fmaf(xv4.w, Mb[(4*q + 3) * 16], a);
    }
    att[(size_t)g * Dz + c] = a;
}

// ---------------------------------------------------------------------------
// K3b: out = att @ Wo^T + bo   (same tiling as K1, no rope)
// ---------------------------------------------------------------------------
__global__ __launch_bounds__(256) void out_gemm_kernel(
    const float* __restrict__ att, const float* __restrict__ Wo,
    const float* __restrict__ bo, float* __restrict__ out)
{
    __shared__ float As[64][36];
    __shared__ float Bs[64][36];
    const int t  = threadIdx.x;
    const int tr = t >> 4;
    const int tc = t & 15;
    const int g0 = blockIdx.x * 64;
    const int n0 = blockIdx.y * 64;

    float acc[4][4];
    #pragma unroll
    for (int i = 0; i < 4; ++i)
        #pragma unroll
        for (int j = 0; j < 4; ++j) acc[i][j] = 0.f;

    for (int k0 = 0; k0 < Dz; k0 += 32) {
        __syncthreads();
        #pragma unroll
        for (int l = 0; l < 8; ++l) {
            int idx = t + l * 256;
            int r = idx >> 5, kk = idx & 31;
            As[r][kk] = att[(size_t)(g0 + r) * Dz + k0 + kk];
            Bs[r][kk] = Wo[(size_t)(n0 + r) * Dz + k0 + kk];
        }
        __syncthreads();
        #pragma unroll
        for (int kk = 0; kk < 32; kk += 4) {
            float4 a4[4], b4[4];
            #pragma unroll
            for (int i = 0; i < 4; ++i) a4[i] = *(const float4*)&As[tr + 16*i][kk];
            #pragma unroll
            for (int j = 0; j < 4; ++j) b4[j] = *(const float4*)&Bs[tc + 16*j][kk];
            #pragma unroll
            for (int i = 0; i < 4; ++i)
                #pragma unroll
                for (int j = 0; j < 4; ++j) {
                    acc[i][j] = fmaf(a4[i].x, b4[j].x, acc[i][j]);
                    acc[i][j] = fmaf(a4[i].y, b4[j].y, acc[i][j]);
                    acc[i][j] = fmaf(a4[i].z, b4[j].z, acc[i][j]);
                    acc[i][j] = fmaf(a4[i].w, b4[j].w, acc[i][j]);
                }
        }
    }

    #pragma unroll
    for (int j = 0; j < 4; ++j) {
        const int c = n0 + tc + 16*j;
        const float bcol = bo[c];
        #pragma unroll
        for (int i = 0; i < 4; ++i) {
            const int g = g0 + tr + 16*i;
            out[(size_t)g * Dz + c] = acc[i][j] + bcol;
        }
    }
}

// ---------------------------------------------------------------------------
extern "C" void kernel_launch(void* const* d_in, const int* in_sizes, int n_in,
                              void* d_out, int out_size, void* d_ws, size_t ws_size,
                              hipStream_t stream)
{
    const float* x    = (const float*)d_in[0];
    const float* wq_w = (const float*)d_in[1];
    const float* wq_b = (const float*)d_in[2];
    // d_in[3], d_in[4] = wk_w, wk_b  (dead in reference no-cache path)
    const float* wv_w = (const float*)d_in[5];
    const float* wv_b = (const float*)d_in[6];
    const float* wo_w = (const float*)d_in[7];
    const float* wo_b = (const float*)d_in[8];

    float* ws  = (float*)d_ws;
    float* xq  = ws;                               // Gz*Dz
    float* xv  = xq  + (size_t)Gz * Dz;            // Gz*Dz
    float* Mm  = xv  + (size_t)Gz * Dz;            // 128*256
    float* att = Mm  + 128 * 256;                  // Gz*Dz
    float* out = (float*)d_out;

    gemm_rope_kernel<<<dim3(Gz/64, Dz/64, 2), 256, 0, stream>>>(
        x, wq_w, wq_b, wv_w, wv_b, xq, xv);
    head_outer_kernel<<<dim3(128), 256, 0, stream>>>(xq, xv, Mm);
    att_kernel<<<dim3(Gz), 256, 0, stream>>>(xq, Mm, att);
    out_gemm_kernel<<<dim3(Gz/64, Dz/64), 256, 0, stream>>>(att, wo_w, wo_b, out);
}

// Round 2
// 103.482 us; speedup vs baseline: 1.5809x; 1.5809x over previous
//
#include <hip/hip_runtime.h>
#include <math.h>

// B=8, S=1024, D=256, H=16, HD=16. Rows G = B*S = 8192.
#define Gz 8192
#define Dz 256
#define Sz 1024

typedef _Float16 half8 __attribute__((ext_vector_type(8)));
typedef float    floatx4 __attribute__((ext_vector_type(4)));

// ---------------------------------------------------------------------------
// K1: xq/xv = fp16( rope(x @ W^T + b) ), W selected by blockIdx.z.
// 64x64 tile, BK=32, 4 waves; wave w owns m-subtile w, all 4 n-subtiles.
// MFMA f32_16x16x32_f16. fp32->fp16 convert fused into LDS staging.
// LDS row stride 40 halfs = 80 B (16B-aligned, <=2-way bank alias = free).
// ---------------------------------------------------------------------------
__global__ __launch_bounds__(256) void qv_gemm_rope(
    const float* __restrict__ x,
    const float* __restrict__ Wq, const float* __restrict__ bq,
    const float* __restrict__ Wv, const float* __restrict__ bv,
    _Float16* __restrict__ xq, _Float16* __restrict__ xv)
{
    __shared__ __align__(16) _Float16 As[64][40];
    __shared__ __align__(16) _Float16 Bs[64][40];
    const int t    = threadIdx.x;
    const int lane = t & 63;
    const int w    = t >> 6;          // wave id 0..3 -> m-subtile
    const int g0   = blockIdx.x * 64;
    const int n0   = blockIdx.y * 64;
    const float* W    = blockIdx.z ? Wv : Wq;
    const float* bias = blockIdx.z ? bv : bq;
    _Float16*    outp = blockIdx.z ? xv : xq;

    const int srow = t >> 2;          // staging row 0..63
    const int skg  = t & 3;           // k-group (8 elems)

    floatx4 acc[4] = {};

    const int fr = lane & 15;         // row-in-tile (A) / col-in-tile (B,C)
    const int kq = lane >> 4;         // k-quad

    for (int k0 = 0; k0 < Dz; k0 += 32) {
        const float* xg = &x[(size_t)(g0 + srow) * Dz + k0 + skg * 8];
        const float* wg = &W[(size_t)(n0 + srow) * Dz + k0 + skg * 8];
        float4 xa = ((const float4*)xg)[0], xb = ((const float4*)xg)[1];
        float4 wa = ((const float4*)wg)[0], wb = ((const float4*)wg)[1];
        half8 ha, hb;
        ha[0]=(_Float16)xa.x; ha[1]=(_Float16)xa.y; ha[2]=(_Float16)xa.z; ha[3]=(_Float16)xa.w;
        ha[4]=(_Float16)xb.x; ha[5]=(_Float16)xb.y; ha[6]=(_Float16)xb.z; ha[7]=(_Float16)xb.w;
        hb[0]=(_Float16)wa.x; hb[1]=(_Float16)wa.y; hb[2]=(_Float16)wa.z; hb[3]=(_Float16)wa.w;
        hb[4]=(_Float16)wb.x; hb[5]=(_Float16)wb.y; hb[6]=(_Float16)wb.z; hb[7]=(_Float16)wb.w;
        __syncthreads();
        *(half8*)&As[srow][skg * 8] = ha;
        *(half8*)&Bs[srow][skg * 8] = hb;
        __syncthreads();
        half8 afrag = *(const half8*)&As[w * 16 + fr][kq * 8];
        #pragma unroll
        for (int j = 0; j < 4; ++j) {
            half8 bfrag = *(const half8*)&Bs[j * 16 + fr][kq * 8];
            acc[j] = __builtin_amdgcn_mfma_f32_16x16x32_f16(afrag, bfrag, acc[j], 0, 0, 0);
        }
    }

    // Epilogue: bias + RoPE (rotor sin + i*cos, 1-indexed pos) + fp16 store.
    // C layout: col = lane&15 (+16j+n0), row = (lane>>4)*4 + reg (+ w*16 + g0).
    // Pair partner col c^1 lives in lane^1 at the same (j, reg).
    #pragma unroll
    for (int j = 0; j < 4; ++j) {
        const int c = n0 + j * 16 + fr;
        const float bcol  = bias[c];
        const float theta = ((c >> 1) < 64) ? 1.0f : 1e-4f;
        const float sign  = (c & 1) ? 1.0f : -1.0f;
        #pragma unroll
        for (int i = 0; i < 4; ++i) {
            const int g = g0 + w * 16 + kq * 4 + i;
            float v = acc[j][i] + bcol;
            float other = __shfl_xor(v, 1, 64);
            float ang = (float)((g & (Sz - 1)) + 1) * theta;
            float sn, cs;
            sincosf(ang, &sn, &cs);
            outp[(size_t)g * Dz + c] = (_Float16)(v * sn + sign * other * cs);
        }
    }
}

// ---------------------------------------------------------------------------
// K2: M[b,h][e][f] = 0.25 * sum_s xq16[b,s,h16+e] * xv16[b,s,h16+f]
// Split-K: grid (128 bh, 8 s-chunks of 128), fp32 atomicAdd into M.
// ---------------------------------------------------------------------------
__global__ __launch_bounds__(256) void head_outer(
    const _Float16* __restrict__ xq, const _Float16* __restrict__ xv,
    float* __restrict__ M)
{
    __shared__ __align__(16) _Float16 qsT[16][136];   // [e][s], pad to 136
    __shared__ __align__(16) _Float16 vsT[16][136];
    const int t  = threadIdx.x;
    const int bh = blockIdx.x;
    const int b  = bh >> 4, h = bh & 15;
    const size_t base = (size_t)b * Sz * Dz + (size_t)blockIdx.y * 128 * Dz + h * 16;

    {
        const int s = t >> 1, eg = t & 1;
        half8 q8 = *(const half8*)&xq[base + (size_t)s * Dz + eg * 8];
        half8 v8 = *(const half8*)&xv[base + (size_t)s * Dz + eg * 8];
        #pragma unroll
        for (int i = 0; i < 8; ++i) {
            qsT[eg * 8 + i][s] = q8[i];
            vsT[eg * 8 + i][s] = v8[i];
        }
    }
    __syncthreads();

    const int e = t >> 4, f = t & 15;
    float acc = 0.f;
    #pragma unroll
    for (int s0 = 0; s0 < 128; s0 += 8) {
        half8 q8 = *(const half8*)&qsT[e][s0];
        half8 v8 = *(const half8*)&vsT[f][s0];
        #pragma unroll
        for (int i = 0; i < 8; ++i) acc += (float)q8[i] * (float)v8[i];
    }
    atomicAdd(&M[(size_t)bh * 256 + t], acc * 0.25f);
}

// ---------------------------------------------------------------------------
// KP: Pt[b][c][h16+e] = fp16( sum_f M[b,h][e][f] * Wo[c][h16+f] )
// Grid 128 (b,h), thread t = column c. out = xq @ Pt^T + bo afterwards.
// ---------------------------------------------------------------------------
__global__ __launch_bounds__(256) void make_p(
    const float* __restrict__ M, const float* __restrict__ Wo,
    _Float16* __restrict__ Pt)
{
    __shared__ float Ms[256];
    const int t  = threadIdx.x;
    const int bh = blockIdx.x;
    const int b  = bh >> 4, h = bh & 15;
    Ms[t] = M[(size_t)bh * 256 + t];
    __syncthreads();

    const int c = t;
    float wo[16];
    const float4* wop = (const float4*)&Wo[(size_t)c * Dz + h * 16];
    #pragma unroll
    for (int q = 0; q < 4; ++q) {
        float4 v = wop[q];
        wo[4*q+0] = v.x; wo[4*q+1] = v.y; wo[4*q+2] = v.z; wo[4*q+3] = v.w;
    }
    half8 lo, hi;
    #pragma unroll
    for (int e = 0; e < 16; ++e) {
        float a = 0.f;
        #pragma unroll
        for (int f = 0; f < 16; ++f) a = fmaf(Ms[e * 16 + f], wo[f], a);
        if (e < 8) lo[e] = (_Float16)a; else hi[e - 8] = (_Float16)a;
    }
    _Float16* dst = &Pt[((size_t)(b * 256 + c)) * Dz + h * 16];
    *(half8*)dst       = lo;
    *(half8*)(dst + 8) = hi;
}

// ---------------------------------------------------------------------------
// K3: out[b*1024+s][c] = sum_r xq16[g][r] * Pt[b][c][r] + bo[c]   (fp32 out)
// Same MFMA skeleton as K1 (no convert, no rope). b = g0>>10.
// ---------------------------------------------------------------------------
__global__ __launch_bounds__(256) void out_gemm(
    const _Float16* __restrict__ xq, const _Float16* __restrict__ Pt,
    const float* __restrict__ bo, float* __restrict__ out)
{
    __shared__ __align__(16) _Float16 As[64][40];
    __shared__ __align__(16) _Float16 Bs[64][40];
    const int t    = threadIdx.x;
    const int lane = t & 63;
    const int w    = t >> 6;
    const int g0   = blockIdx.x * 64;
    const int n0   = blockIdx.y * 64;
    const int b    = g0 >> 10;

    const int srow = t >> 2;
    const int skg  = t & 3;
    const int fr   = lane & 15;
    const int kq   = lane >> 4;

    floatx4 acc[4] = {};

    for (int k0 = 0; k0 < Dz; k0 += 32) {
        half8 ha = *(const half8*)&xq[(size_t)(g0 + srow) * Dz + k0 + skg * 8];
        half8 hb = *(const half8*)&Pt[((size_t)(b * 256 + n0 + srow)) * Dz + k0 + skg * 8];
        __syncthreads();
        *(half8*)&As[srow][skg * 8] = ha;
        *(half8*)&Bs[srow][skg * 8] = hb;
        __syncthreads();
        half8 afrag = *(const half8*)&As[w * 16 + fr][kq * 8];
        #pragma unroll
        for (int j = 0; j < 4; ++j) {
            half8 bfrag = *(const half8*)&Bs[j * 16 + fr][kq * 8];
            acc[j] = __builtin_amdgcn_mfma_f32_16x16x32_f16(afrag, bfrag, acc[j], 0, 0, 0);
        }
    }

    #pragma unroll
    for (int j = 0; j < 4; ++j) {
        const int c = n0 + j * 16 + fr;
        const float bcol = bo[c];
        #pragma unroll
        for (int i = 0; i < 4; ++i) {
            const int g = g0 + w * 16 + kq * 4 + i;
            out[(size_t)g * Dz + c] = acc[j][i] + bcol;
        }
    }
}

// ---------------------------------------------------------------------------
extern "C" void kernel_launch(void* const* d_in, const int* in_sizes, int n_in,
                              void* d_out, int out_size, void* d_ws, size_t ws_size,
                              hipStream_t stream)
{
    const float* x    = (const float*)d_in[0];
    const float* wq_w = (const float*)d_in[1];
    const float* wq_b = (const float*)d_in[2];
    // d_in[3], d_in[4] = wk_w, wk_b : dead in the no-cache reference path
    const float* wv_w = (const float*)d_in[5];
    const float* wv_b = (const float*)d_in[6];
    const float* wo_w = (const float*)d_in[7];
    const float* wo_b = (const float*)d_in[8];

    _Float16* xq16 = (_Float16*)d_ws;                    // Gz*Dz halfs (4 MB)
    _Float16* xv16 = xq16 + (size_t)Gz * Dz;             // Gz*Dz halfs (4 MB)
    _Float16* Pt   = xv16 + (size_t)Gz * Dz;             // 8*256*256 halfs (1 MB)
    float*    M    = (float*)(Pt + (size_t)8 * 256 * 256);  // 128*256 fp32
    float*    out  = (float*)d_out;

    hipMemsetAsync(M, 0, 128 * 256 * sizeof(float), stream);
    qv_gemm_rope<<<dim3(Gz / 64, Dz / 64, 2), 256, 0, stream>>>(
        x, wq_w, wq_b, wv_w, wv_b, xq16, xv16);
    head_outer<<<dim3(128, 8), 256, 0, stream>>>(xq16, xv16, M);
    make_p<<<dim3(128), 256, 0, stream>>>(M, wo_w, Pt);
    out_gemm<<<dim3(Gz / 64, Dz / 64), 256, 0, stream>>>(xq16, Pt, wo_b, out);
}

// Round 3
// 102.255 us; speedup vs baseline: 1.5999x; 1.0120x over previous
//
#include <hip/hip_runtime.h>

// B=8, S=1024, D=256, H=16, HD=16. Rows G = B*S = 8192.
#define Gz 8192
#define Dz 256
#define Sz 1024

typedef _Float16 half8 __attribute__((ext_vector_type(8)));
typedef float    floatx4 __attribute__((ext_vector_type(4)));

// width-16 async global->LDS (wave-uniform base + lane*16 layout required)
#define GLOAD_LDS(gptr, lptr)                                                      \
    __builtin_amdgcn_global_load_lds(                                              \
        (const __attribute__((address_space(1))) void*)(gptr),                     \
        (__attribute__((address_space(3))) void*)(lptr), 16, 0, 0)

__device__ inline half8 cvt8(const float* __restrict__ p) {
    float4 a = ((const float4*)p)[0];
    float4 b = ((const float4*)p)[1];
    half8 h;
    h[0]=(_Float16)a.x; h[1]=(_Float16)a.y; h[2]=(_Float16)a.z; h[3]=(_Float16)a.w;
    h[4]=(_Float16)b.x; h[5]=(_Float16)b.y; h[6]=(_Float16)b.z; h[7]=(_Float16)b.w;
    return h;
}

// ---------------------------------------------------------------------------
// K0: x -> fp16 x16 [8192x256]; pack [Wq;Wv] -> fp16 w16 [512x256].
// ---------------------------------------------------------------------------
__global__ __launch_bounds__(256) void convert_kernel(
    const float* __restrict__ x, const float* __restrict__ wq,
    const float* __restrict__ wv,
    _Float16* __restrict__ x16, _Float16* __restrict__ w16)
{
    size_t e = ((size_t)blockIdx.x * 256 + threadIdx.x) * 8;
    const float* src;
    _Float16* dst;
    if (e < (size_t)Gz * Dz) { src = x + e; dst = x16 + e; }
    else {
        size_t e2 = e - (size_t)Gz * Dz;        // 0 .. 131071
        dst = w16 + e2;
        src = (e2 < 65536) ? (wq + e2) : (wv + (e2 - 65536));
    }
    *(half8*)dst = cvt8(src);
}

// ---------------------------------------------------------------------------
// K1: C[8192x512] = x16 @ w16^T, +bias, RoPE, fp16 out -> xq (cols<256)/xv.
// 128x128 tile, BK=64, global_load_lds width16, 4 waves each 64x64.
// ---------------------------------------------------------------------------
__global__ __launch_bounds__(256) void qv_gemm_rope(
    const _Float16* __restrict__ x16, const _Float16* __restrict__ w16,
    const float* __restrict__ bq, const float* __restrict__ bv,
    _Float16* __restrict__ xq, _Float16* __restrict__ xv)
{
    __shared__ _Float16 As[128 * 64];   // unpadded: global_load_lds layout
    __shared__ _Float16 Bs[128 * 64];
    const int t = threadIdx.x, lane = t & 63, w = t >> 6;
    const int g0 = blockIdx.x * 128;
    const int by = blockIdx.y;              // 0..3 -> cols [by*128, +128)
    const int n0 = by * 128;
    const int wm = (w >> 1) * 64, wn = (w & 1) * 64;
    const int fr = lane & 15, kq = lane >> 4;

    floatx4 acc[4][4] = {};

    for (int k0 = 0; k0 < Dz; k0 += 64) {
        __syncthreads();
        #pragma unroll
        for (int p = 0; p < 4; ++p) {
            const int flat = (t + 256 * p) * 8;
            const int row = flat >> 6, col = flat & 63;
            GLOAD_LDS(x16 + (size_t)(g0 + row) * Dz + k0 + col, &As[flat]);
            GLOAD_LDS(w16 + (size_t)(n0 + row) * Dz + k0 + col, &Bs[flat]);
        }
        __syncthreads();
        #pragma unroll
        for (int ks = 0; ks < 2; ++ks) {
            const int kk = ks * 32 + kq * 8;
            half8 a[4], b[4];
            #pragma unroll
            for (int i = 0; i < 4; ++i) a[i] = *(const half8*)&As[(wm + i * 16 + fr) * 64 + kk];
            #pragma unroll
            for (int j = 0; j < 4; ++j) b[j] = *(const half8*)&Bs[(wn + j * 16 + fr) * 64 + kk];
            #pragma unroll
            for (int i = 0; i < 4; ++i)
                #pragma unroll
                for (int j = 0; j < 4; ++j)
                    acc[i][j] = __builtin_amdgcn_mfma_f32_16x16x32_f16(a[i], b[j], acc[i][j], 0, 0, 0);
        }
    }

    // Epilogue. C layout: col=lane&15 (n side), row=kq*4+reg (m side).
    // theta is block-uniform: cols of this block sit entirely in one half.
    const int qside = (by < 2);
    const float* bias = qside ? bq : bv;
    _Float16* outp = qside ? xq : xv;
    const float theta = (by & 1) ? 1e-4f : 1.0f;
    const float sign  = (fr & 1) ? 1.0f : -1.0f;

    float sn[4][4], cs[4][4];
    #pragma unroll
    for (int i = 0; i < 4; ++i)
        #pragma unroll
        for (int r = 0; r < 4; ++r) {
            const int g = g0 + wm + i * 16 + kq * 4 + r;
            const float pos = (float)((g & (Sz - 1)) + 1);
            __sincosf(pos * theta, &sn[i][r], &cs[i][r]);
        }

    #pragma unroll
    for (int j = 0; j < 4; ++j) {
        const int ch = (by & 1) * 128 + wn + j * 16 + fr;   // col within 256
        const float bcol = bias[ch];
        #pragma unroll
        for (int i = 0; i < 4; ++i)
            #pragma unroll
            for (int r = 0; r < 4; ++r) {
                const int g = g0 + wm + i * 16 + kq * 4 + r;
                float v = acc[i][j][r] + bcol;
                float other = __shfl_xor(v, 1, 64);   // pair partner col ch^1
                outp[(size_t)g * Dz + ch] =
                    (_Float16)(v * sn[i][r] + sign * other * cs[i][r]);
            }
    }
}

// ---------------------------------------------------------------------------
// K2: split-K head outer products. Mpart[chunk][bh][e*16+f] =
//     sum_{s in chunk} xq[b,s,h16+e]*xv[b,s,h16+f]. No atomics.
// ---------------------------------------------------------------------------
__global__ __launch_bounds__(256) void head_outer(
    const _Float16* __restrict__ xq, const _Float16* __restrict__ xv,
    float* __restrict__ Mpart)
{
    __shared__ __align__(16) _Float16 qsT[16][136];
    __shared__ __align__(16) _Float16 vsT[16][136];
    const int t = threadIdx.x;
    const int bh = blockIdx.x;
    const int b = bh >> 4, h = bh & 15;
    const size_t base = (size_t)b * Sz * Dz + (size_t)blockIdx.y * 128 * Dz + h * 16;

    {
        const int s = t >> 1, eg = t & 1;
        half8 q8 = *(const half8*)&xq[base + (size_t)s * Dz + eg * 8];
        half8 v8 = *(const half8*)&xv[base + (size_t)s * Dz + eg * 8];
        #pragma unroll
        for (int i = 0; i < 8; ++i) {
            qsT[eg * 8 + i][s] = q8[i];
            vsT[eg * 8 + i][s] = v8[i];
        }
    }
    __syncthreads();

    const int e = t >> 4, f = t & 15;
    float acc = 0.f;
    #pragma unroll
    for (int s0 = 0; s0 < 128; s0 += 8) {
        half8 q8 = *(const half8*)&qsT[e][s0];
        half8 v8 = *(const half8*)&vsT[f][s0];
        #pragma unroll
        for (int i = 0; i < 8; ++i) acc += (float)q8[i] * (float)v8[i];
    }
    Mpart[((size_t)blockIdx.y * 128 + bh) * 256 + t] = acc;
}

// ---------------------------------------------------------------------------
// KP: Pt[b][c][h16+e] = fp16( 0.25 * sum_f M[b,h][e][f] * Wo[c][h16+f] )
// ---------------------------------------------------------------------------
__global__ __launch_bounds__(256) void make_p(
    const float* __restrict__ Mpart, const float* __restrict__ Wo,
    _Float16* __restrict__ Pt)
{
    __shared__ float Ms[256];
    const int t = threadIdx.x;
    const int bh = blockIdx.x;
    const int b = bh >> 4, h = bh & 15;
    float s = 0.f;
    #pragma unroll
    for (int c = 0; c < 8; ++c) s += Mpart[((size_t)c * 128 + bh) * 256 + t];
    Ms[t] = s * 0.25f;
    __syncthreads();

    const int c = t;
    float wo[16];
    const float4* wop = (const float4*)&Wo[(size_t)c * Dz + h * 16];
    #pragma unroll
    for (int q = 0; q < 4; ++q) {
        float4 v = wop[q];
        wo[4*q+0] = v.x; wo[4*q+1] = v.y; wo[4*q+2] = v.z; wo[4*q+3] = v.w;
    }
    half8 lo, hi;
    #pragma unroll
    for (int e = 0; e < 16; ++e) {
        float a = 0.f;
        #pragma unroll
        for (int f = 0; f < 16; ++f) a = fmaf(Ms[e * 16 + f], wo[f], a);
        if (e < 8) lo[e] = (_Float16)a; else hi[e - 8] = (_Float16)a;
    }
    _Float16* dst = &Pt[((size_t)(b * 256 + c)) * Dz + h * 16];
    *(half8*)dst       = lo;
    *(half8*)(dst + 8) = hi;
}

// ---------------------------------------------------------------------------
// K3: out[g][c] = sum_r xq16[g][r] * Pt[b][c][r] + bo[c], fp32 out.
// 64x128 tile, BK=64, grid (128,2) = 256 blocks. Waves each 32x64.
// ---------------------------------------------------------------------------
__global__ __launch_bounds__(256) void out_gemm(
    const _Float16* __restrict__ xq, const _Float16* __restrict__ Pt,
    const float* __restrict__ bo, float* __restrict__ out)
{
    __shared__ _Float16 As[64 * 64];
    __shared__ _Float16 Bs[128 * 64];
    const int t = threadIdx.x, lane = t & 63, w = t >> 6;
    const int g0 = blockIdx.x * 64;
    const int n0 = blockIdx.y * 128;
    const int b  = g0 >> 10;
    const int wm = (w >> 1) * 32, wn = (w & 1) * 64;
    const int fr = lane & 15, kq = lane >> 4;
    const _Float16* Pb = Pt + (size_t)b * 256 * Dz;

    floatx4 acc[2][4] = {};

    for (int k0 = 0; k0 < Dz; k0 += 64) {
        __syncthreads();
        #pragma unroll
        for (int p = 0; p < 2; ++p) {
            const int flat = (t + 256 * p) * 8;
            const int row = flat >> 6, col = flat & 63;
            GLOAD_LDS(xq + (size_t)(g0 + row) * Dz + k0 + col, &As[flat]);
        }
        #pragma unroll
        for (int p = 0; p < 4; ++p) {
            const int flat = (t + 256 * p) * 8;
            const int row = flat >> 6, col = flat & 63;
            GLOAD_LDS(Pb + (size_t)(n0 + row) * Dz + k0 + col, &Bs[flat]);
        }
        __syncthreads();
        #pragma unroll
        for (int ks = 0; ks < 2; ++ks) {
            const int kk = ks * 32 + kq * 8;
            half8 a[2], bf[4];
            #pragma unroll
            for (int i = 0; i < 2; ++i) a[i] = *(const half8*)&As[(wm + i * 16 + fr) * 64 + kk];
            #pragma unroll
            for (int j = 0; j < 4; ++j) bf[j] = *(const half8*)&Bs[(wn + j * 16 + fr) * 64 + kk];
            #pragma unroll
            for (int i = 0; i < 2; ++i)
                #pragma unroll
                for (int j = 0; j < 4; ++j)
                    acc[i][j] = __builtin_amdgcn_mfma_f32_16x16x32_f16(a[i], bf[j], acc[i][j], 0, 0, 0);
        }
    }

    #pragma unroll
    for (int j = 0; j < 4; ++j) {
        const int c = n0 + wn + j * 16 + fr;
        const float bcol = bo[c];
        #pragma unroll
        for (int i = 0; i < 2; ++i)
            #pragma unroll
            for (int r = 0; r < 4; ++r) {
                const int g = g0 + wm + i * 16 + kq * 4 + r;
                out[(size_t)g * Dz + c] = acc[i][j][r] + bcol;
            }
    }
}

// ---------------------------------------------------------------------------
extern "C" void kernel_launch(void* const* d_in, const int* in_sizes, int n_in,
                              void* d_out, int out_size, void* d_ws, size_t ws_size,
                              hipStream_t stream)
{
    const float* x    = (const float*)d_in[0];
    const float* wq_w = (const float*)d_in[1];
    const float* wq_b = (const float*)d_in[2];
    // d_in[3], d_in[4] = wk_w, wk_b : dead in the no-cache reference path
    const float* wv_w = (const float*)d_in[5];
    const float* wv_b = (const float*)d_in[6];
    const float* wo_w = (const float*)d_in[7];
    const float* wo_b = (const float*)d_in[8];

    _Float16* x16  = (_Float16*)d_ws;                    // 2M halfs
    _Float16* w16  = x16  + (size_t)Gz * Dz;             // 131072 halfs
    _Float16* xq16 = w16  + 131072;                      // 2M halfs
    _Float16* xv16 = xq16 + (size_t)Gz * Dz;             // 2M halfs
    _Float16* Pt   = xv16 + (size_t)Gz * Dz;             // 524288 halfs
    float*    Mpart = (float*)(Pt + 524288);             // 8*128*256 floats
    float*    out  = (float*)d_out;

    convert_kernel<<<dim3((Gz * Dz + 131072) / 2048), 256, 0, stream>>>(
        x, wq_w, wv_w, x16, w16);
    qv_gemm_rope<<<dim3(Gz / 128, 4), 256, 0, stream>>>(
        x16, w16, wq_b, wv_b, xq16, xv16);
    head_outer<<<dim3(128, 8), 256, 0, stream>>>(xq16, xv16, Mpart);
    make_p<<<dim3(128), 256, 0, stream>>>(Mpart, wo_w, Pt);
    out_gemm<<<dim3(Gz / 64, 2), 256, 0, stream>>>(xq16, Pt, wo_b, out);
}